// Round 8
// baseline (530.740 us; speedup 1.0000x reference)
//
#include <hip/hip_runtime.h>
#include <cmath>

typedef _Float16 f16;
typedef _Float16 f16x8 __attribute__((ext_vector_type(8)));
typedef float f32x4 __attribute__((ext_vector_type(4)));
typedef unsigned long long u64;

#define M_OUT 2049          // N//2 + 1
#define NDIM 4096
#define MPAD 2112           // 2049 padded to 64-multiple (33 tiles)
// reference: -2.0 * 3.14 / N computed in f64, rounded once to f32
#define CW ((float)(-2.0 * 3.14 / 4096.0))

// ws layout:
//   [0, 16384)             row means (4096 f32)
//   [16384, 16384+2049*8)  argmax cells (u64, packed (amp2_bits<<32)|~col)
//   [40960, ...)           tables (layout depends on path)
// FULL path (chunk-major):
//   A tables: Ach,Acl,Ash,Asl each [512][2112][8] f16   (4 x 17.3 MB)
//     (cl/sl store RAW residual v-(f16)v, for merged accumulation)
//   X tables: Xh,Xl           each [512][4096][8] f16   (2 x 33.6 MB)
// The A-table region doubles as SCRATCH for the Nyquist partials (512 KB),
// consumed by nyq_reduce BEFORE fill_tables_cm overwrites it (stream order).
// MID path (row-major): Ach,Acl,Ash,Asl each [2112][4096] f16 (x64-scaled lo)
static const size_t WS_MEAN  = 0;
static const size_t WS_CELLS = 16384;
static const size_t WS_TBL   = 40960;
static const size_t A_ELEMS  = (size_t)MPAD * NDIM;        // 8650752
static const size_t X_ELEMS  = (size_t)NDIM * NDIM;        // 16777216
static const size_t WS_XTBL  = WS_TBL + 4 * A_ELEMS * sizeof(f16);
static const size_t WS_FULL_END = WS_XTBL + 2 * X_ELEMS * sizeof(f16);
static const size_t WS_MID_END  = WS_TBL + 4 * A_ELEMS * sizeof(f16);

#define AS1 __attribute__((address_space(1)))
#define AS3 __attribute__((address_space(3)))
__device__ __forceinline__ void async_copy16(const void* gsrc, void* ldst) {
    __builtin_amdgcn_global_load_lds((const AS1 unsigned int*)gsrc,
                                     (AS3 unsigned int*)ldst, 16, 0, 0);
}

// x64-scaled split (fallback path)
__device__ __forceinline__ void split_f16(float v, f16& hi, f16& lo) {
    hi = (f16)v;
    lo = (f16)((v - (float)hi) * 64.0f);
}
// raw-residual split (cm path, merged accumulators)
__device__ __forceinline__ void split_raw(float v, f16& hi, f16& lo) {
    hi = (f16)v;
    lo = (f16)(v - (float)hi);
}

// ---------------- row means (+ argmax-cell init in first 9 blocks) ----------------
__global__ void mean_kernel(const float* __restrict__ x, float* __restrict__ meanv,
                            u64* __restrict__ cells) {
    if (blockIdx.x < 9) {
        int i = blockIdx.x * 256 + threadIdx.x;
        if (i < M_OUT) cells[i] = 0ull;
    }
    const int row = blockIdx.x;
    const float4* xr = (const float4*)(x + (size_t)row * NDIM);
    float s = 0.f;
    for (int i = threadIdx.x; i < NDIM / 4; i += 256) {
        float4 v = xr[i];
        s += (v.x + v.y) + (v.z + v.w);
    }
    for (int off = 32; off; off >>= 1) s += __shfl_down(s, off);
    __shared__ float ps[4];
    if ((threadIdx.x & 63) == 0) ps[threadIdx.x >> 6] = s;
    __syncthreads();
    if (threadIdx.x == 0) {
        float t = (ps[0] + ps[1]) + (ps[2] + ps[3]);
        meanv[row] = t * (1.0f / 4096.0f);
    }
}

// ---------------- Nyquist row (m = 2048), two-stage deterministic f32 ----------
__global__ __launch_bounds__(256) void nyq_partial(
    const float* __restrict__ x, const float* __restrict__ meanv,
    float* __restrict__ part)     // [2][16][4096] f32 = 512 KB
{
    __shared__ float lc[256], ls[256];
    __shared__ float sC[128], sS[128];
    const int t = threadIdx.x;
    const int ks = blockIdx.y;                 // 0..15
    const int kbase = ks * 256;
    sincosf(CW * (float)(2048 * (kbase + t)), &ls[t], &lc[t]);
    __syncthreads();
    const int col = blockIdx.x * 128 + (t & 127);
    const int kp  = t >> 7;                    // 0/1
    float C = 0.f, S = 0.f;
    const float* xp = x + (size_t)(kbase + kp * 128) * NDIM + col;
    const float* mp = meanv + kbase + kp * 128;
    for (int i = 0; i < 128; ++i) {
        float v = xp[(size_t)i * NDIM] - mp[i];
        C = fmaf(lc[kp * 128 + i], v, C);
        S = fmaf(ls[kp * 128 + i], v, S);
    }
    if (kp) { sC[t - 128] = C; sS[t - 128] = S; }
    __syncthreads();
    if (!kp) {
        part[(size_t)ks * NDIM + col]            = C + sC[t];
        part[(size_t)(16 + ks) * NDIM + col]     = S + sS[t];
    }
}

__global__ __launch_bounds__(256) void nyq_reduce(
    const float* __restrict__ part, u64* __restrict__ cells)
{
    const int n = blockIdx.x * 256 + threadIdx.x;   // 16 blocks
    float C = 0.f, S = 0.f;
    for (int ks = 0; ks < 16; ++ks) {
        C += part[(size_t)ks * NDIM + n];
        S += part[(size_t)(16 + ks) * NDIM + n];
    }
    float a2 = C * C + S * S;
    u64 key = ((u64)__float_as_uint(a2) << 32) | (unsigned)(~n);
    for (int off = 1; off < 64; off <<= 1) {
        unsigned hi = (unsigned)(key >> 32), lo = (unsigned)key;
        unsigned ho = __shfl_xor(hi, off), lo2 = __shfl_xor(lo, off);
        u64 o = ((u64)ho << 32) | lo2;
        if (o > key) key = o;
    }
    if ((threadIdx.x & 63) == 0) atomicMax(cells + 2048, key);
}

// ================= FULL path: chunk-major tables (A + X merged, one launch) ========
// grid (512, 25): y in [0,9) -> A-table rows tile, y in [9,25) -> X-table col tile.
// Low tables store RAW residuals (merged-accumulator numerics).
__global__ void fill_tables_cm(const float* __restrict__ x, const float* __restrict__ meanv,
                               f16* __restrict__ atbl, f16* __restrict__ xtbl) {
    const int c = blockIdx.x;                      // k-chunk 0..511
    if (blockIdx.y < 9) {
        const int m = blockIdx.y * 256 + threadIdx.x;  // 0..2303
        if (m >= MPAD) return;
        const bool valid = (m < M_OUT);
        f16x8 chv, clv, shv, slv;
        for (int j = 0; j < 8; ++j) {
            float cc = 0.f, ss = 0.f;
            if (valid) {
                int kk = c * 8 + j;
                float ang = CW * (float)(m * kk);      // m*kk < 2^24 -> exact
                sincosf(ang, &ss, &cc);
            }
            f16 h, l;
            split_raw(cc, h, l); chv[j] = h; clv[j] = l;
            split_raw(ss, h, l); shv[j] = h; slv[j] = l;
        }
        size_t idx = ((size_t)c * MPAD + m) * 8;
        *(f16x8*)(atbl + idx)                 = chv;
        *(f16x8*)(atbl + A_ELEMS + idx)       = clv;
        *(f16x8*)(atbl + 2 * A_ELEMS + idx)   = shv;
        *(f16x8*)(atbl + 3 * A_ELEMS + idx)   = slv;
    } else {
        const int n = (blockIdx.y - 9) * 256 + threadIdx.x;  // 0..4095
        f16x8 hv, lv;
        for (int j = 0; j < 8; ++j) {
            int k = c * 8 + j;
            float v = x[(size_t)k * NDIM + n] - meanv[k];
            f16 h, l;
            split_raw(v, h, l);
            hv[j] = h; lv[j] = l;
        }
        size_t idx = ((size_t)c * NDIM + n) * 8;
        *(f16x8*)(xtbl + idx)           = hv;
        *(f16x8*)(xtbl + X_ELEMS + idx) = lv;
    }
}

// Fused split-f16 DFT GEMM + argmax — 4 blocks/CU (max-TLP) variant.
// The schedule experiments (r0-r2: counted vmcnt, barrier-free) were all neutral;
// the levers that worked are PACKING (r4) and REGISTERS (r7: VGPR 72). This round
// converts both into occupancy: merged accumulators (64 VGPR) + single-buffered
// A regs (32) + DOUBLE-buffered X LDS (32 KB) -> 4 blocks/CU, 16 waves/CU,
// and 1024 blocks = EXACTLY ONE dispatch round (no tail at all).
// Simple drain-barrier pipeline (round-0 style, WAR-safe with 2 buffers:
// restage-after-barrier; DMA lands before next barrier's vmcnt(0) drain).
// Stall holes of one block are filled by the other 3 (m114 MFMA/VALU overlap).
// Tile: BM=64 x BN=128 x BK=32. 256 threads = 4 waves (2x2 of 32x64).
__global__ __launch_bounds__(256, 4) void dft_gemm_cm(
    const f16* __restrict__ atbl, const f16* __restrict__ xtbl,
    u64* __restrict__ cells)
{
    __shared__ alignas(16) f16 sX[2][2][4][128][8];   // [buf][tbl][plane][n][8] = 32 KB

    const int t = threadIdx.x;
    const int n0      = blockIdx.x * 128;
    const int rowBase = blockIdx.y * 64;

    const int lane = t & 63;
    const int w  = t >> 6;
    const int wm = w >> 1, wn = w & 1;
    const int q  = lane >> 4, ln = lane & 15;

    f32x4 aC[2][4], aS[2][4];
#pragma unroll
    for (int i = 0; i < 2; ++i)
#pragma unroll
        for (int j = 0; j < 4; ++j) {
            aC[i][j] = (f32x4){0.f, 0.f, 0.f, 0.f};
            aS[i][j] = (f32x4){0.f, 0.f, 0.f, 0.f};
        }

    // A-fragment global base: row = rowBase + wm*32 + tm*16 + ln, chunk = kc + q
    const f16* aBase = atbl + ((size_t)q * MPAD + (rowBase + wm * 32 + ln)) * 8;

    // X staging: 4 async ops per wave cover [2 tables][4 planes][2 halves]
    const int xq0 = w >> 1, xh = w & 1;
    const int xq1 = xq0 + 2;
    const f16* xG0 = xtbl + ((size_t)xq0 * NDIM + n0 + xh * 64 + lane) * 8;
    const f16* xG1 = xtbl + ((size_t)xq1 * NDIM + n0 + xh * 64 + lane) * 8;
    const f16* xG2 = xG0 + X_ELEMS;
    const f16* xG3 = xG1 + X_ELEMS;

    auto loadA = [&](f16x8 (&dst)[2][4], int kc) {
#pragma unroll
        for (int tm = 0; tm < 2; ++tm)
#pragma unroll
            for (int tb = 0; tb < 4; ++tb)
                dst[tm][tb] = *(const f16x8*)(aBase + (size_t)tb * A_ELEMS
                              + ((size_t)kc * MPAD + tm * 16) * 8);
    };

    auto stageX = [&](int buf, int kc) {
        const size_t kadv = (size_t)kc * NDIM * 8;
        async_copy16(xG0 + kadv, &sX[buf][0][xq0][xh * 64][0]);
        async_copy16(xG1 + kadv, &sX[buf][0][xq1][xh * 64][0]);
        async_copy16(xG2 + kadv, &sX[buf][1][xq0][xh * 64][0]);
        async_copy16(xG3 + kadv, &sX[buf][1][xq1][xh * 64][0]);
    };

    auto compute = [&](f16x8 (&A)[2][4], int buf) {
        f16x8 bh[4], bl[4];
#pragma unroll
        for (int tn = 0; tn < 4; ++tn) {
            int nl = wn * 64 + tn * 16 + ln;
            bh[tn] = *(const f16x8*)&sX[buf][0][q][nl][0];
            bl[tn] = *(const f16x8*)&sX[buf][1][q][nl][0];
        }
        __builtin_amdgcn_s_setprio(1);
#pragma unroll
        for (int tm = 0; tm < 2; ++tm)
#pragma unroll
            for (int tn = 0; tn < 4; ++tn) {
                aC[tm][tn] = __builtin_amdgcn_mfma_f32_16x16x32_f16(A[tm][0], bh[tn], aC[tm][tn], 0, 0, 0);
                aC[tm][tn] = __builtin_amdgcn_mfma_f32_16x16x32_f16(A[tm][0], bl[tn], aC[tm][tn], 0, 0, 0);
                aC[tm][tn] = __builtin_amdgcn_mfma_f32_16x16x32_f16(A[tm][1], bh[tn], aC[tm][tn], 0, 0, 0);
                aS[tm][tn] = __builtin_amdgcn_mfma_f32_16x16x32_f16(A[tm][2], bh[tn], aS[tm][tn], 0, 0, 0);
                aS[tm][tn] = __builtin_amdgcn_mfma_f32_16x16x32_f16(A[tm][2], bl[tn], aS[tm][tn], 0, 0, 0);
                aS[tm][tn] = __builtin_amdgcn_mfma_f32_16x16x32_f16(A[tm][3], bh[tn], aS[tm][tn], 0, 0, 0);
            }
        __builtin_amdgcn_s_setprio(0);
    };

    f16x8 Aa[2][4];
    int cur = 0;

    // prologue: X for phase 0 in flight (drained by first __syncthreads)
    stageX(0, 0);

    // 128 phases (kc = 0,4,...,508), double-buffered X, drain barrier per phase
    for (int kc = 0; kc < 512; kc += 4) {
        __syncthreads();                       // buf(cur) DMA landed; prev readers done
        if (kc + 4 < 512) stageX(cur ^ 1, kc + 4);
        loadA(Aa, kc);
        compute(Aa, cur);
        cur ^= 1;
    }

    // ---- epilogue: amp^2, per-row argmax, atomicMax into cells ----
#pragma unroll
    for (int tm = 0; tm < 2; ++tm) {
#pragma unroll
        for (int r = 0; r < 4; ++r) {
            u64 best = 0ull;
#pragma unroll
            for (int tn = 0; tn < 4; ++tn) {
                float C = aC[tm][tn][r];
                float S = aS[tm][tn][r];
                float a2 = C * C + S * S;
                int col = n0 + wn * 64 + tn * 16 + ln;
                u64 key = ((u64)__float_as_uint(a2) << 32) | (unsigned)(~col);
                if (key > best) best = key;
            }
            for (int off = 1; off < 16; off <<= 1) {
                unsigned hi = (unsigned)(best >> 32), lo = (unsigned)best;
                unsigned ho = __shfl_xor(hi, off);
                unsigned lo2 = __shfl_xor(lo, off);
                u64 o = ((u64)ho << 32) | lo2;
                if (o > best) best = o;
            }
            if (ln == 0) {
                int grow = rowBase + wm * 32 + tm * 16 + q * 4 + r;
                if (grow < M_OUT) atomicMax(cells + grow, best);
            }
        }
    }
}

// ================= MID/LOW fallback path (unchanged, x64-scaled lo) ===========
__global__ void fill_tables_rm(f16* __restrict__ tbl) {
    long long g = (long long)blockIdx.x * 256 + threadIdx.x;
    if (g >= (long long)(MPAD * 512)) return;
    int m  = (int)(g >> 9);
    int kq = ((int)g & 511) * 8;
    bool valid = (m < M_OUT);
    f16x8 chv, clv, shv, slv;
    for (int j = 0; j < 8; ++j) {
        float c = 0.f, s = 0.f;
        if (valid) {
            int kk = kq + j;
            float ang = CW * (float)(m * kk);
            sincosf(ang, &s, &c);
        }
        f16 h, l;
        split_f16(c, h, l); chv[j] = h; clv[j] = l;
        split_f16(s, h, l); shv[j] = h; slv[j] = l;
    }
    size_t idx = (size_t)m * NDIM + kq;
    *(f16x8*)(tbl + idx)               = chv;
    *(f16x8*)(tbl + A_ELEMS + idx)     = clv;
    *(f16x8*)(tbl + 2 * A_ELEMS + idx) = shv;
    *(f16x8*)(tbl + 3 * A_ELEMS + idx) = slv;
}

#define PK 40   // padded k-stride: all 8 bank groups covered -> 2-way (free)
__global__ __launch_bounds__(256, 2) void dft_gemm_fb(
    const float* __restrict__ x, const float* __restrict__ meanv,
    const f16* __restrict__ tbl, int useTbl,
    u64* __restrict__ cells)
{
    __shared__ alignas(16) f16 Ach[64][PK];
    __shared__ alignas(16) f16 Acl[64][PK];
    __shared__ alignas(16) f16 Ash[64][PK];
    __shared__ alignas(16) f16 Asl[64][PK];
    __shared__ alignas(16) f16 Xh[128][PK];
    __shared__ alignas(16) f16 Xl[128][PK];

    const int t = threadIdx.x;
    const int n0      = blockIdx.x * 128;
    const int rowBase = blockIdx.y * 64;

    const int am  = t >> 2;
    const int akq = (t & 3) * 8;
    const int xn  = t & 127;
    const int xkh = (t >> 7) * 16;

    const int lane = t & 63;
    const int w  = t >> 6;
    const int wm = w >> 1, wn = w & 1;
    const int q  = lane >> 4, ln = lane & 15;

    f32x4 aC0[2][4], aC1[2][4], aS0[2][4], aS1[2][4];
    for (int i = 0; i < 2; ++i)
        for (int j = 0; j < 4; ++j) {
            aC0[i][j] = (f32x4){0.f, 0.f, 0.f, 0.f};
            aC1[i][j] = (f32x4){0.f, 0.f, 0.f, 0.f};
            aS0[i][j] = (f32x4){0.f, 0.f, 0.f, 0.f};
            aS1[i][j] = (f32x4){0.f, 0.f, 0.f, 0.f};
        }

    const int arow = rowBase + am;
    const bool avalid = (arow < M_OUT);

    for (int k0 = 0; k0 < NDIM; k0 += 32) {
        __syncthreads();
        if (useTbl) {
            size_t idx = (size_t)arow * NDIM + k0 + akq;
            *(f16x8*)&Ach[am][akq] = *(const f16x8*)(tbl + idx);
            *(f16x8*)&Acl[am][akq] = *(const f16x8*)(tbl + A_ELEMS + idx);
            *(f16x8*)&Ash[am][akq] = *(const f16x8*)(tbl + 2 * A_ELEMS + idx);
            *(f16x8*)&Asl[am][akq] = *(const f16x8*)(tbl + 3 * A_ELEMS + idx);
        } else {
            f16x8 chv, clv, shv, slv;
            for (int j = 0; j < 8; ++j) {
                float c = 0.f, s = 0.f;
                if (avalid) {
                    int kk = k0 + akq + j;
                    float ang = CW * (float)(arow * kk);
                    sincosf(ang, &s, &c);
                }
                f16 h, l;
                split_f16(c, h, l); chv[j] = h; clv[j] = l;
                split_f16(s, h, l); shv[j] = h; slv[j] = l;
            }
            *(f16x8*)&Ach[am][akq] = chv;
            *(f16x8*)&Acl[am][akq] = clv;
            *(f16x8*)&Ash[am][akq] = shv;
            *(f16x8*)&Asl[am][akq] = slv;
        }
        {
            const float* xp = x + (size_t)(k0 + xkh) * NDIM + n0 + xn;
            f16x8 h0, h1, l0, l1;
            for (int r = 0; r < 16; ++r) {
                float v = xp[(size_t)r * NDIM] - meanv[k0 + xkh + r];
                f16 hi, lo;
                split_f16(v, hi, lo);
                if (r < 8) { h0[r] = hi; l0[r] = lo; }
                else       { h1[r - 8] = hi; l1[r - 8] = lo; }
            }
            *(f16x8*)&Xh[xn][xkh]     = h0;
            *(f16x8*)&Xh[xn][xkh + 8] = h1;
            *(f16x8*)&Xl[xn][xkh]     = l0;
            *(f16x8*)&Xl[xn][xkh + 8] = l1;
        }
        __syncthreads();
        f16x8 fch[2], fcl[2], fsh[2], fsl[2], bh[4], bl[4];
        for (int tm = 0; tm < 2; ++tm) {
            int ml = wm * 32 + tm * 16 + ln;
            fch[tm] = *(const f16x8*)&Ach[ml][q * 8];
            fcl[tm] = *(const f16x8*)&Acl[ml][q * 8];
            fsh[tm] = *(const f16x8*)&Ash[ml][q * 8];
            fsl[tm] = *(const f16x8*)&Asl[ml][q * 8];
        }
        for (int tn = 0; tn < 4; ++tn) {
            int nl = wn * 64 + tn * 16 + ln;
            bh[tn] = *(const f16x8*)&Xh[nl][q * 8];
            bl[tn] = *(const f16x8*)&Xl[nl][q * 8];
        }
        for (int tm = 0; tm < 2; ++tm)
            for (int tn = 0; tn < 4; ++tn) {
                aC0[tm][tn] = __builtin_amdgcn_mfma_f32_16x16x32_f16(fch[tm], bh[tn], aC0[tm][tn], 0, 0, 0);
                aC1[tm][tn] = __builtin_amdgcn_mfma_f32_16x16x32_f16(fch[tm], bl[tn], aC1[tm][tn], 0, 0, 0);
                aC1[tm][tn] = __builtin_amdgcn_mfma_f32_16x16x32_f16(fcl[tm], bh[tn], aC1[tm][tn], 0, 0, 0);
                aS0[tm][tn] = __builtin_amdgcn_mfma_f32_16x16x32_f16(fsh[tm], bh[tn], aS0[tm][tn], 0, 0, 0);
                aS1[tm][tn] = __builtin_amdgcn_mfma_f32_16x16x32_f16(fsh[tm], bl[tn], aS1[tm][tn], 0, 0, 0);
                aS1[tm][tn] = __builtin_amdgcn_mfma_f32_16x16x32_f16(fsl[tm], bh[tn], aS1[tm][tn], 0, 0, 0);
            }
    }

    const float inv64 = 0.015625f;
    for (int tm = 0; tm < 2; ++tm) {
        for (int r = 0; r < 4; ++r) {
            u64 best = 0ull;
            for (int tn = 0; tn < 4; ++tn) {
                float C = aC0[tm][tn][r] + aC1[tm][tn][r] * inv64;
                float S = aS0[tm][tn][r] + aS1[tm][tn][r] * inv64;
                float a2 = C * C + S * S;
                int col = n0 + wn * 64 + tn * 16 + ln;
                u64 key = ((u64)__float_as_uint(a2) << 32) | (unsigned)(~col);
                if (key > best) best = key;
            }
            for (int off = 1; off < 16; off <<= 1) {
                unsigned hi = (unsigned)(best >> 32), lo = (unsigned)best;
                unsigned ho = __shfl_xor(hi, off);
                unsigned lo2 = __shfl_xor(lo, off);
                u64 o = ((u64)ho << 32) | lo2;
                if (o > best) best = o;
            }
            if (ln == 0) {
                int grow = rowBase + wm * 32 + tm * 16 + q * 4 + r;
                if (grow < M_OUT) atomicMax(cells + grow, best);
            }
        }
    }
}

// ---------------- cells -> output ----------------
__global__ void out_kernel(const u64* __restrict__ cells, float* __restrict__ out) {
    int i = blockIdx.x * 256 + threadIdx.x;
    if (i < M_OUT) {
        unsigned col = ~(unsigned)(cells[i] & 0xFFFFFFFFull);
        float freq = (float)col / (4096.0f / 30.0f);
        out[i] = freq * 60.0f;
    }
}

extern "C" void kernel_launch(void* const* d_in, const int* in_sizes, int n_in,
                              void* d_out, int out_size, void* d_ws, size_t ws_size,
                              hipStream_t stream) {
    const float* x = (const float*)d_in[0];
    char* ws = (char*)d_ws;
    float* meanv = (float*)(ws + WS_MEAN);
    u64*   cells = (u64*)(ws + WS_CELLS);
    f16*   atbl  = (f16*)(ws + WS_TBL);
    f16*   xtbl  = (f16*)(ws + WS_XTBL);
    float* nyqp  = (float*)(ws + WS_TBL);   // scratch, consumed before table fill
    float* out   = (float*)d_out;

    hipLaunchKernelGGL(mean_kernel, dim3(NDIM), dim3(256), 0, stream, x, meanv, cells);

    if (ws_size >= WS_FULL_END) {
        // Nyquist row first (uses A-table region as scratch, then freed)
        hipLaunchKernelGGL(nyq_partial, dim3(32, 16), dim3(256), 0, stream, x, meanv, nyqp);
        hipLaunchKernelGGL(nyq_reduce, dim3(16), dim3(256), 0, stream, nyqp, cells);
        hipLaunchKernelGGL(fill_tables_cm, dim3(512, 25), dim3(256), 0, stream,
                           x, meanv, atbl, xtbl);
        // rows 0..2047: 1024 blocks at 4 blocks/CU = exactly ONE dispatch round
        hipLaunchKernelGGL(dft_gemm_cm, dim3(32, 32), dim3(256), 0, stream, atbl, xtbl, cells);
    } else if (ws_size >= WS_MID_END) {
        hipLaunchKernelGGL(fill_tables_rm, dim3(4224), dim3(256), 0, stream, atbl);
        hipLaunchKernelGGL(dft_gemm_fb, dim3(32, 33), dim3(256), 0, stream,
                           x, meanv, atbl, 1, cells);
    } else {
        hipLaunchKernelGGL(dft_gemm_fb, dim3(32, 33), dim3(256), 0, stream,
                           x, meanv, atbl, 0, cells);
    }
    hipLaunchKernelGGL(out_kernel, dim3((M_OUT + 255) / 256), dim3(256), 0, stream, cells, out);
}

// Round 9
// 451.739 us; speedup vs baseline: 1.1749x; 1.1749x over previous
//
#include <hip/hip_runtime.h>
#include <cmath>

typedef _Float16 f16;
typedef _Float16 f16x8 __attribute__((ext_vector_type(8)));
typedef float f32x4 __attribute__((ext_vector_type(4)));
typedef unsigned long long u64;

#define M_OUT 2049          // N//2 + 1
#define NDIM 4096
#define MPAD 2112           // 2049 padded to 64-multiple (33 tiles)
// reference: -2.0 * 3.14 / N computed in f64, rounded once to f32
#define CW ((float)(-2.0 * 3.14 / 4096.0))

// ws layout:
//   [0, 16384)             row means (4096 f32)
//   [16384, 16384+2049*8)  argmax cells (u64, packed (amp2_bits<<32)|~col)
//   [40960, ...)           tables (layout depends on path)
// FULL path (chunk-major):
//   A tables: Ach,Acl,Ash,Asl each [512][2112][8] f16   (4 x 17.3 MB)
//     (cl/sl store RAW residual v-(f16)v, for merged accumulation)
//   X tables: Xh,Xl           each [512][4096][8] f16   (2 x 33.6 MB)
// The A-table region doubles as SCRATCH for the Nyquist partials (512 KB),
// consumed by nyq_reduce BEFORE fill_tables_cm overwrites it (stream order).
// MID path (row-major): Ach,Acl,Ash,Asl each [2112][4096] f16 (x64-scaled lo)
static const size_t WS_MEAN  = 0;
static const size_t WS_CELLS = 16384;
static const size_t WS_TBL   = 40960;
static const size_t A_ELEMS  = (size_t)MPAD * NDIM;        // 8650752
static const size_t X_ELEMS  = (size_t)NDIM * NDIM;        // 16777216
static const size_t WS_XTBL  = WS_TBL + 4 * A_ELEMS * sizeof(f16);
static const size_t WS_FULL_END = WS_XTBL + 2 * X_ELEMS * sizeof(f16);
static const size_t WS_MID_END  = WS_TBL + 4 * A_ELEMS * sizeof(f16);

#define AS1 __attribute__((address_space(1)))
#define AS3 __attribute__((address_space(3)))
__device__ __forceinline__ void async_copy16(const void* gsrc, void* ldst) {
    __builtin_amdgcn_global_load_lds((const AS1 unsigned int*)gsrc,
                                     (AS3 unsigned int*)ldst, 16, 0, 0);
}

// x64-scaled split (fallback path)
__device__ __forceinline__ void split_f16(float v, f16& hi, f16& lo) {
    hi = (f16)v;
    lo = (f16)((v - (float)hi) * 64.0f);
}
// raw-residual split (cm path, merged accumulators)
__device__ __forceinline__ void split_raw(float v, f16& hi, f16& lo) {
    hi = (f16)v;
    lo = (f16)(v - (float)hi);
}

// ---------------- row means (+ argmax-cell init in first 9 blocks) ----------------
__global__ void mean_kernel(const float* __restrict__ x, float* __restrict__ meanv,
                            u64* __restrict__ cells) {
    if (blockIdx.x < 9) {
        int i = blockIdx.x * 256 + threadIdx.x;
        if (i < M_OUT) cells[i] = 0ull;
    }
    const int row = blockIdx.x;
    const float4* xr = (const float4*)(x + (size_t)row * NDIM);
    float s = 0.f;
    for (int i = threadIdx.x; i < NDIM / 4; i += 256) {
        float4 v = xr[i];
        s += (v.x + v.y) + (v.z + v.w);
    }
    for (int off = 32; off; off >>= 1) s += __shfl_down(s, off);
    __shared__ float ps[4];
    if ((threadIdx.x & 63) == 0) ps[threadIdx.x >> 6] = s;
    __syncthreads();
    if (threadIdx.x == 0) {
        float t = (ps[0] + ps[1]) + (ps[2] + ps[3]);
        meanv[row] = t * (1.0f / 4096.0f);
    }
}

// ---------------- Nyquist row (m = 2048), two-stage deterministic f32 ----------
__global__ __launch_bounds__(256) void nyq_partial(
    const float* __restrict__ x, const float* __restrict__ meanv,
    float* __restrict__ part)     // [2][16][4096] f32 = 512 KB
{
    __shared__ float lc[256], ls[256];
    __shared__ float sC[128], sS[128];
    const int t = threadIdx.x;
    const int ks = blockIdx.y;                 // 0..15
    const int kbase = ks * 256;
    sincosf(CW * (float)(2048 * (kbase + t)), &ls[t], &lc[t]);
    __syncthreads();
    const int col = blockIdx.x * 128 + (t & 127);
    const int kp  = t >> 7;                    // 0/1
    float C = 0.f, S = 0.f;
    const float* xp = x + (size_t)(kbase + kp * 128) * NDIM + col;
    const float* mp = meanv + kbase + kp * 128;
    for (int i = 0; i < 128; ++i) {
        float v = xp[(size_t)i * NDIM] - mp[i];
        C = fmaf(lc[kp * 128 + i], v, C);
        S = fmaf(ls[kp * 128 + i], v, S);
    }
    if (kp) { sC[t - 128] = C; sS[t - 128] = S; }
    __syncthreads();
    if (!kp) {
        part[(size_t)ks * NDIM + col]            = C + sC[t];
        part[(size_t)(16 + ks) * NDIM + col]     = S + sS[t];
    }
}

__global__ __launch_bounds__(256) void nyq_reduce(
    const float* __restrict__ part, u64* __restrict__ cells)
{
    const int n = blockIdx.x * 256 + threadIdx.x;   // 16 blocks
    float C = 0.f, S = 0.f;
    for (int ks = 0; ks < 16; ++ks) {
        C += part[(size_t)ks * NDIM + n];
        S += part[(size_t)(16 + ks) * NDIM + n];
    }
    float a2 = C * C + S * S;
    u64 key = ((u64)__float_as_uint(a2) << 32) | (unsigned)(~n);
    for (int off = 1; off < 64; off <<= 1) {
        unsigned hi = (unsigned)(key >> 32), lo = (unsigned)key;
        unsigned ho = __shfl_xor(hi, off), lo2 = __shfl_xor(lo, off);
        u64 o = ((u64)ho << 32) | lo2;
        if (o > key) key = o;
    }
    if ((threadIdx.x & 63) == 0) atomicMax(cells + 2048, key);
}

// ================= FULL path: chunk-major tables (A + X merged, one launch) ========
// grid (512, 25): y in [0,9) -> A-table rows tile, y in [9,25) -> X-table col tile.
// Low tables store RAW residuals (merged-accumulator numerics).
__global__ void fill_tables_cm(const float* __restrict__ x, const float* __restrict__ meanv,
                               f16* __restrict__ atbl, f16* __restrict__ xtbl) {
    const int c = blockIdx.x;                      // k-chunk 0..511
    if (blockIdx.y < 9) {
        const int m = blockIdx.y * 256 + threadIdx.x;  // 0..2303
        if (m >= MPAD) return;
        const bool valid = (m < M_OUT);
        f16x8 chv, clv, shv, slv;
        for (int j = 0; j < 8; ++j) {
            float cc = 0.f, ss = 0.f;
            if (valid) {
                int kk = c * 8 + j;
                float ang = CW * (float)(m * kk);      // m*kk < 2^24 -> exact
                sincosf(ang, &ss, &cc);
            }
            f16 h, l;
            split_raw(cc, h, l); chv[j] = h; clv[j] = l;
            split_raw(ss, h, l); shv[j] = h; slv[j] = l;
        }
        size_t idx = ((size_t)c * MPAD + m) * 8;
        *(f16x8*)(atbl + idx)                 = chv;
        *(f16x8*)(atbl + A_ELEMS + idx)       = clv;
        *(f16x8*)(atbl + 2 * A_ELEMS + idx)   = shv;
        *(f16x8*)(atbl + 3 * A_ELEMS + idx)   = slv;
    } else {
        const int n = (blockIdx.y - 9) * 256 + threadIdx.x;  // 0..4095
        f16x8 hv, lv;
        for (int j = 0; j < 8; ++j) {
            int k = c * 8 + j;
            float v = x[(size_t)k * NDIM + n] - meanv[k];
            f16 h, l;
            split_raw(v, h, l);
            hv[j] = h; lv[j] = l;
        }
        size_t idx = ((size_t)c * NDIM + n) * 8;
        *(f16x8*)(xtbl + idx)           = hv;
        *(f16x8*)(xtbl + X_ELEMS + idx) = lv;
    }
}

// Fused split-f16 DFT GEMM + argmax — WIDE-TILE single-round variant.
// r8 lesson: 4 blocks/CU spills (WRITE_SIZE 300 MB). Instead spend the merged-acc
// register savings on tile WIDTH at the proven 2 blocks/CU: BM=64 x BN=256,
// grid 16x32 = 512 blocks = EXACTLY one dispatch round, zero tail. Per phase a
// wave now issues 96 MFMAs vs 48 while per-phase overhead (barrier, 8 A-loads,
// vmcnt) is ~constant -> overhead fraction halves (r6: 63% util @48).
// Pipeline per K=32 phase (double-buffered X, 2x32 KB):
//   s_barrier                      (retires all reads of buf cur^1)
//   loadA(kc)        8 vmem        (this phase's A)
//   stageX(cur^1)    8 DMA         (next phase's X; safe: readers retired)
//   s_waitcnt vmcnt(8)             (drains stage(cur)+loadA; 8 new DMAs fly on)
//   compute(cur)     96 MFMA       (setprio-wrapped)
// Regs: acc 128 (merged, AGPR) + A 32 + temps ~40 -> fits 2 waves/SIMD (256).
// Tile: BM=64 x BN=256 x BK=32. 256 threads = 4 waves (2x2 of 32x128).
__global__ __launch_bounds__(256, 2) void dft_gemm_cm(
    const f16* __restrict__ atbl, const f16* __restrict__ xtbl,
    u64* __restrict__ cells)
{
    __shared__ alignas(16) f16 sX[2][2][4][256][8];   // [buf][tbl][plane][n][8] = 64 KB

    const int t = threadIdx.x;
    const int n0      = blockIdx.x * 256;
    const int rowBase = blockIdx.y * 64;

    const int lane = t & 63;
    const int w  = t >> 6;
    const int wm = w >> 1, wn = w & 1;
    const int q  = lane >> 4, ln = lane & 15;

    f32x4 aC[2][8], aS[2][8];
#pragma unroll
    for (int i = 0; i < 2; ++i)
#pragma unroll
        for (int j = 0; j < 8; ++j) {
            aC[i][j] = (f32x4){0.f, 0.f, 0.f, 0.f};
            aS[i][j] = (f32x4){0.f, 0.f, 0.f, 0.f};
        }

    // A-fragment global base: row = rowBase + wm*32 + tm*16 + ln, chunk = kc + q
    const f16* aBase = atbl + ((size_t)q * MPAD + (rowBase + wm * 32 + ln)) * 8;
    // X DMA source base: wave w stages cols [w*64, w*64+64), per-lane col w*64+lane
    const f16* xBase = xtbl + (size_t)(n0 + w * 64 + lane) * 8;

    auto loadA = [&](f16x8 (&dst)[2][4], int kc) {
#pragma unroll
        for (int tm = 0; tm < 2; ++tm)
#pragma unroll
            for (int tb = 0; tb < 4; ++tb)
                dst[tm][tb] = *(const f16x8*)(aBase + (size_t)tb * A_ELEMS
                              + ((size_t)kc * MPAD + tm * 16) * 8);
    };

    // 8 DMAs per wave: [2 tables][4 planes] x own 64-col slice
    auto stageX = [&](int buf, int kc) {
        const f16* src = xBase + (size_t)kc * (NDIM * 8);
#pragma unroll
        for (int tb = 0; tb < 2; ++tb)
#pragma unroll
            for (int p = 0; p < 4; ++p)
                async_copy16(src + (size_t)tb * X_ELEMS + (size_t)p * (NDIM * 8),
                             &sX[buf][tb][p][w * 64][0]);
    };

    auto compute = [&](f16x8 (&A)[2][4], int buf) {
        __builtin_amdgcn_s_setprio(1);
#pragma unroll
        for (int tn = 0; tn < 8; ++tn) {
            int nl = wn * 128 + tn * 16 + ln;
            f16x8 bh = *(const f16x8*)&sX[buf][0][q][nl][0];
            f16x8 bl = *(const f16x8*)&sX[buf][1][q][nl][0];
#pragma unroll
            for (int tm = 0; tm < 2; ++tm) {
                aC[tm][tn] = __builtin_amdgcn_mfma_f32_16x16x32_f16(A[tm][0], bh, aC[tm][tn], 0, 0, 0);
                aC[tm][tn] = __builtin_amdgcn_mfma_f32_16x16x32_f16(A[tm][0], bl, aC[tm][tn], 0, 0, 0);
                aC[tm][tn] = __builtin_amdgcn_mfma_f32_16x16x32_f16(A[tm][1], bh, aC[tm][tn], 0, 0, 0);
                aS[tm][tn] = __builtin_amdgcn_mfma_f32_16x16x32_f16(A[tm][2], bh, aS[tm][tn], 0, 0, 0);
                aS[tm][tn] = __builtin_amdgcn_mfma_f32_16x16x32_f16(A[tm][2], bl, aS[tm][tn], 0, 0, 0);
                aS[tm][tn] = __builtin_amdgcn_mfma_f32_16x16x32_f16(A[tm][3], bh, aS[tm][tn], 0, 0, 0);
            }
        }
        __builtin_amdgcn_s_setprio(0);
    };

    f16x8 Aa[2][4];
    int cur = 0;

    // prologue: X for phase 0 in flight (drained by first vmcnt(8))
    stageX(0, 0);

    // 128 phases (kc = 0,4,...,508)
    for (int kc = 0; kc < 512; kc += 4) {
        __builtin_amdgcn_s_barrier();              // all reads of buf cur^1 retired
        __builtin_amdgcn_sched_barrier(0);
        loadA(Aa, kc);
        __builtin_amdgcn_sched_barrier(0);
        if (kc + 4 < 512) {
            stageX(cur ^ 1, kc + 4);
            __builtin_amdgcn_sched_barrier(0);
            asm volatile("s_waitcnt vmcnt(8)" ::: "memory");  // stage(cur)+loadA done
        } else {
            asm volatile("s_waitcnt vmcnt(0)" ::: "memory");
        }
        __builtin_amdgcn_sched_barrier(0);
        compute(Aa, cur);
        cur ^= 1;
    }

    // ---- epilogue: amp^2, per-row argmax, atomicMax into cells ----
#pragma unroll
    for (int tm = 0; tm < 2; ++tm) {
#pragma unroll
        for (int r = 0; r < 4; ++r) {
            u64 best = 0ull;
#pragma unroll
            for (int tn = 0; tn < 8; ++tn) {
                float C = aC[tm][tn][r];
                float S = aS[tm][tn][r];
                float a2 = C * C + S * S;
                int col = n0 + wn * 128 + tn * 16 + ln;
                u64 key = ((u64)__float_as_uint(a2) << 32) | (unsigned)(~col);
                if (key > best) best = key;
            }
            for (int off = 1; off < 16; off <<= 1) {
                unsigned hi = (unsigned)(best >> 32), lo = (unsigned)best;
                unsigned ho = __shfl_xor(hi, off);
                unsigned lo2 = __shfl_xor(lo, off);
                u64 o = ((u64)ho << 32) | lo2;
                if (o > best) best = o;
            }
            if (ln == 0) {
                int grow = rowBase + wm * 32 + tm * 16 + q * 4 + r;
                if (grow < M_OUT) atomicMax(cells + grow, best);
            }
        }
    }
}

// ================= MID/LOW fallback path (unchanged, x64-scaled lo) ===========
__global__ void fill_tables_rm(f16* __restrict__ tbl) {
    long long g = (long long)blockIdx.x * 256 + threadIdx.x;
    if (g >= (long long)(MPAD * 512)) return;
    int m  = (int)(g >> 9);
    int kq = ((int)g & 511) * 8;
    bool valid = (m < M_OUT);
    f16x8 chv, clv, shv, slv;
    for (int j = 0; j < 8; ++j) {
        float c = 0.f, s = 0.f;
        if (valid) {
            int kk = kq + j;
            float ang = CW * (float)(m * kk);
            sincosf(ang, &s, &c);
        }
        f16 h, l;
        split_f16(c, h, l); chv[j] = h; clv[j] = l;
        split_f16(s, h, l); shv[j] = h; slv[j] = l;
    }
    size_t idx = (size_t)m * NDIM + kq;
    *(f16x8*)(tbl + idx)               = chv;
    *(f16x8*)(tbl + A_ELEMS + idx)     = clv;
    *(f16x8*)(tbl + 2 * A_ELEMS + idx) = shv;
    *(f16x8*)(tbl + 3 * A_ELEMS + idx) = slv;
}

#define PK 40   // padded k-stride: all 8 bank groups covered -> 2-way (free)
__global__ __launch_bounds__(256, 2) void dft_gemm_fb(
    const float* __restrict__ x, const float* __restrict__ meanv,
    const f16* __restrict__ tbl, int useTbl,
    u64* __restrict__ cells)
{
    __shared__ alignas(16) f16 Ach[64][PK];
    __shared__ alignas(16) f16 Acl[64][PK];
    __shared__ alignas(16) f16 Ash[64][PK];
    __shared__ alignas(16) f16 Asl[64][PK];
    __shared__ alignas(16) f16 Xh[128][PK];
    __shared__ alignas(16) f16 Xl[128][PK];

    const int t = threadIdx.x;
    const int n0      = blockIdx.x * 128;
    const int rowBase = blockIdx.y * 64;

    const int am  = t >> 2;
    const int akq = (t & 3) * 8;
    const int xn  = t & 127;
    const int xkh = (t >> 7) * 16;

    const int lane = t & 63;
    const int w  = t >> 6;
    const int wm = w >> 1, wn = w & 1;
    const int q  = lane >> 4, ln = lane & 15;

    f32x4 aC0[2][4], aC1[2][4], aS0[2][4], aS1[2][4];
    for (int i = 0; i < 2; ++i)
        for (int j = 0; j < 4; ++j) {
            aC0[i][j] = (f32x4){0.f, 0.f, 0.f, 0.f};
            aC1[i][j] = (f32x4){0.f, 0.f, 0.f, 0.f};
            aS0[i][j] = (f32x4){0.f, 0.f, 0.f, 0.f};
            aS1[i][j] = (f32x4){0.f, 0.f, 0.f, 0.f};
        }

    const int arow = rowBase + am;
    const bool avalid = (arow < M_OUT);

    for (int k0 = 0; k0 < NDIM; k0 += 32) {
        __syncthreads();
        if (useTbl) {
            size_t idx = (size_t)arow * NDIM + k0 + akq;
            *(f16x8*)&Ach[am][akq] = *(const f16x8*)(tbl + idx);
            *(f16x8*)&Acl[am][akq] = *(const f16x8*)(tbl + A_ELEMS + idx);
            *(f16x8*)&Ash[am][akq] = *(const f16x8*)(tbl + 2 * A_ELEMS + idx);
            *(f16x8*)&Asl[am][akq] = *(const f16x8*)(tbl + 3 * A_ELEMS + idx);
        } else {
            f16x8 chv, clv, shv, slv;
            for (int j = 0; j < 8; ++j) {
                float c = 0.f, s = 0.f;
                if (avalid) {
                    int kk = k0 + akq + j;
                    float ang = CW * (float)(arow * kk);
                    sincosf(ang, &s, &c);
                }
                f16 h, l;
                split_f16(c, h, l); chv[j] = h; clv[j] = l;
                split_f16(s, h, l); shv[j] = h; slv[j] = l;
            }
            *(f16x8*)&Ach[am][akq] = chv;
            *(f16x8*)&Acl[am][akq] = clv;
            *(f16x8*)&Ash[am][akq] = shv;
            *(f16x8*)&Asl[am][akq] = slv;
        }
        {
            const float* xp = x + (size_t)(k0 + xkh) * NDIM + n0 + xn;
            f16x8 h0, h1, l0, l1;
            for (int r = 0; r < 16; ++r) {
                float v = xp[(size_t)r * NDIM] - meanv[k0 + xkh + r];
                f16 hi, lo;
                split_f16(v, hi, lo);
                if (r < 8) { h0[r] = hi; l0[r] = lo; }
                else       { h1[r - 8] = hi; l1[r - 8] = lo; }
            }
            *(f16x8*)&Xh[xn][xkh]     = h0;
            *(f16x8*)&Xh[xn][xkh + 8] = h1;
            *(f16x8*)&Xl[xn][xkh]     = l0;
            *(f16x8*)&Xl[xn][xkh + 8] = l1;
        }
        __syncthreads();
        f16x8 fch[2], fcl[2], fsh[2], fsl[2], bh[4], bl[4];
        for (int tm = 0; tm < 2; ++tm) {
            int ml = wm * 32 + tm * 16 + ln;
            fch[tm] = *(const f16x8*)&Ach[ml][q * 8];
            fcl[tm] = *(const f16x8*)&Acl[ml][q * 8];
            fsh[tm] = *(const f16x8*)&Ash[ml][q * 8];
            fsl[tm] = *(const f16x8*)&Asl[ml][q * 8];
        }
        for (int tn = 0; tn < 4; ++tn) {
            int nl = wn * 64 + tn * 16 + ln;
            bh[tn] = *(const f16x8*)&Xh[nl][q * 8];
            bl[tn] = *(const f16x8*)&Xl[nl][q * 8];
        }
        for (int tm = 0; tm < 2; ++tm)
            for (int tn = 0; tn < 4; ++tn) {
                aC0[tm][tn] = __builtin_amdgcn_mfma_f32_16x16x32_f16(fch[tm], bh[tn], aC0[tm][tn], 0, 0, 0);
                aC1[tm][tn] = __builtin_amdgcn_mfma_f32_16x16x32_f16(fch[tm], bl[tn], aC1[tm][tn], 0, 0, 0);
                aC1[tm][tn] = __builtin_amdgcn_mfma_f32_16x16x32_f16(fcl[tm], bh[tn], aC1[tm][tn], 0, 0, 0);
                aS0[tm][tn] = __builtin_amdgcn_mfma_f32_16x16x32_f16(fsh[tm], bh[tn], aS0[tm][tn], 0, 0, 0);
                aS1[tm][tn] = __builtin_amdgcn_mfma_f32_16x16x32_f16(fsh[tm], bl[tn], aS1[tm][tn], 0, 0, 0);
                aS1[tm][tn] = __builtin_amdgcn_mfma_f32_16x16x32_f16(fsl[tm], bh[tn], aS1[tm][tn], 0, 0, 0);
            }
    }

    const float inv64 = 0.015625f;
    for (int tm = 0; tm < 2; ++tm) {
        for (int r = 0; r < 4; ++r) {
            u64 best = 0ull;
            for (int tn = 0; tn < 4; ++tn) {
                float C = aC0[tm][tn][r] + aC1[tm][tn][r] * inv64;
                float S = aS0[tm][tn][r] + aS1[tm][tn][r] * inv64;
                float a2 = C * C + S * S;
                int col = n0 + wn * 64 + tn * 16 + ln;
                u64 key = ((u64)__float_as_uint(a2) << 32) | (unsigned)(~col);
                if (key > best) best = key;
            }
            for (int off = 1; off < 16; off <<= 1) {
                unsigned hi = (unsigned)(best >> 32), lo = (unsigned)best;
                unsigned ho = __shfl_xor(hi, off);
                unsigned lo2 = __shfl_xor(lo, off);
                u64 o = ((u64)ho << 32) | lo2;
                if (o > best) best = o;
            }
            if (ln == 0) {
                int grow = rowBase + wm * 32 + tm * 16 + q * 4 + r;
                if (grow < M_OUT) atomicMax(cells + grow, best);
            }
        }
    }
}

// ---------------- cells -> output ----------------
__global__ void out_kernel(const u64* __restrict__ cells, float* __restrict__ out) {
    int i = blockIdx.x * 256 + threadIdx.x;
    if (i < M_OUT) {
        unsigned col = ~(unsigned)(cells[i] & 0xFFFFFFFFull);
        float freq = (float)col / (4096.0f / 30.0f);
        out[i] = freq * 60.0f;
    }
}

extern "C" void kernel_launch(void* const* d_in, const int* in_sizes, int n_in,
                              void* d_out, int out_size, void* d_ws, size_t ws_size,
                              hipStream_t stream) {
    const float* x = (const float*)d_in[0];
    char* ws = (char*)d_ws;
    float* meanv = (float*)(ws + WS_MEAN);
    u64*   cells = (u64*)(ws + WS_CELLS);
    f16*   atbl  = (f16*)(ws + WS_TBL);
    f16*   xtbl  = (f16*)(ws + WS_XTBL);
    float* nyqp  = (float*)(ws + WS_TBL);   // scratch, consumed before table fill
    float* out   = (float*)d_out;

    hipLaunchKernelGGL(mean_kernel, dim3(NDIM), dim3(256), 0, stream, x, meanv, cells);

    if (ws_size >= WS_FULL_END) {
        // Nyquist row first (uses A-table region as scratch, then freed)
        hipLaunchKernelGGL(nyq_partial, dim3(32, 16), dim3(256), 0, stream, x, meanv, nyqp);
        hipLaunchKernelGGL(nyq_reduce, dim3(16), dim3(256), 0, stream, nyqp, cells);
        hipLaunchKernelGGL(fill_tables_cm, dim3(512, 25), dim3(256), 0, stream,
                           x, meanv, atbl, xtbl);
        // rows 0..2047: 16x32 = 512 blocks at 2 blocks/CU = exactly ONE round
        hipLaunchKernelGGL(dft_gemm_cm, dim3(16, 32), dim3(256), 0, stream, atbl, xtbl, cells);
    } else if (ws_size >= WS_MID_END) {
        hipLaunchKernelGGL(fill_tables_rm, dim3(4224), dim3(256), 0, stream, atbl);
        hipLaunchKernelGGL(dft_gemm_fb, dim3(32, 33), dim3(256), 0, stream,
                           x, meanv, atbl, 1, cells);
    } else {
        hipLaunchKernelGGL(dft_gemm_fb, dim3(32, 33), dim3(256), 0, stream,
                           x, meanv, atbl, 0, cells);
    }
    hipLaunchKernelGGL(out_kernel, dim3((M_OUT + 255) / 256), dim3(256), 0, stream, cells, out);
}